// Round 8
// baseline (452.727 us; speedup 1.0000x reference)
//
#include <hip/hip_runtime.h>

#define NB 32      // B
#define NS 8192    // S
#define NH 256     // H
#define NR 256     // RIN
#define NQ 256     // QIN

typedef __bf16 bf16x8 __attribute__((ext_vector_type(8)));
typedef float  f32x4  __attribute__((ext_vector_type(4)));

__device__ __forceinline__ float fast_tanh(float x) {
  x = fminf(15.0f, fmaxf(-15.0f, x));
  float e = __expf(2.0f * x);
  return (e - 1.0f) * __builtin_amdgcn_rcpf(e + 1.0f);
}

// split 8 consecutive f32 into bf16 hi + bf16 lo (RNE): x ~= hi + lo
__device__ __forceinline__ void split8(float4 a, float4 b, bf16x8& hi, bf16x8& lo) {
  float x[8] = {a.x, a.y, a.z, a.w, b.x, b.y, b.z, b.w};
#pragma unroll
  for (int j = 0; j < 8; ++j) {
    __bf16 h = (__bf16)x[j];
    hi[j] = h;
    lo[j] = (__bf16)(x[j] - (float)h);
  }
}

// blocks 0..31: q[b,h] = query[b,:]@Wq[h,:] + bq[h]
// blocks 32..63: split Wr into fragment-linear hi/lo bf16: [ks][mtile][lane][8]
__global__ __launch_bounds__(256) void prep_kernel(
    const float* __restrict__ query, const float* __restrict__ Wq,
    const float* __restrict__ bq, const float* __restrict__ Wr,
    float* __restrict__ ws_q, __bf16* __restrict__ wsAhi, __bf16* __restrict__ wsAlo) {
  const int tid = threadIdx.x;
  const int blk = blockIdx.x;
  if (blk < NB) {
    const float4* qr = reinterpret_cast<const float4*>(query + blk * NQ);
    const float4* wr = reinterpret_cast<const float4*>(Wq + tid * NQ);
    float acc = 0.0f;
#pragma unroll 8
    for (int i = 0; i < NQ / 4; ++i) {
      float4 a = qr[i], w = wr[i];
      acc += a.x * w.x + a.y * w.y + a.z * w.z + a.w * w.w;
    }
    ws_q[blk * NH + tid] = acc + bq[tid];
  } else {
    const int gid = (blk - NB) * 256 + tid;   // [ks(8)][mt(16)][lane(64)]
    const int l  = gid & 63;
    const int mt = (gid >> 6) & 15;
    const int ks = gid >> 10;
    const int row = 16 * mt + (l & 15);
    const int kb  = 32 * ks + 8 * (l >> 4);
    const float4* src = reinterpret_cast<const float4*>(Wr + row * NR + kb);
    bf16x8 hi, lo;
    split8(src[0], src[1], hi, lo);
    *reinterpret_cast<bf16x8*>(wsAhi + (size_t)gid * 8) = hi;
    *reinterpret_cast<bf16x8*>(wsAlo + (size_t)gid * 8) = lo;
  }
}

// R7 ABLATION: template over MODE.
//  0 = full/real (exact R0 structure)   — launched LAST, produces final d_out
//  1 = full minus e-store (u real)      — e-store marginal
//  2 = epilogue-only (k-loop skipped)   — tanh + store cost
//  3 = loop-only (acc -> 1 float/block) — staging + MFMA cost
// Probes write only d_out regions that MODE 0 fully overwrites afterwards.
template<int MODE>
__global__ __launch_bounds__(256, 2) void attn_t(
    const float* __restrict__ ref, const float* __restrict__ br,
    const float* __restrict__ v, const float* __restrict__ ws_q,
    const __bf16* __restrict__ wsAhi, const __bf16* __restrict__ wsAlo,
    float* __restrict__ e_out, float* __restrict__ u_out) {
  __shared__ __bf16 lXhi[4 * 64 * 8];   // frag-linear: [ntile(4)][lane(64)][8]
  __shared__ __bf16 lXlo[4 * 64 * 8];
  __shared__ float  u_part[4][64];

  const int tid = threadIdx.x;
  const int l   = tid & 63;
  const int wm  = tid >> 6;
  const int s0  = blockIdx.x * 64;
  const int b   = blockIdx.y;

  const float* srcX = ref + (size_t)(s0 + 16 * wm + (l & 15)) * (NB * NR)
                          + (size_t)b * NR + 8 * (l >> 4);

  f32x4 acc[4][4];
  const f32x4 zero = {0.f, 0.f, 0.f, 0.f};
#pragma unroll
  for (int mt = 0; mt < 4; ++mt)
#pragma unroll
    for (int nt = 0; nt < 4; ++nt) acc[mt][nt] = zero;

  if constexpr (MODE != 2) {
#pragma unroll 1
    for (int ks = 0; ks < NR / 32; ++ks) {
      bf16x8 ah[4], al[4];
#pragma unroll
      for (int mt = 0; mt < 4; ++mt) {
        const size_t fo = ((size_t)(ks * 16 + wm * 4 + mt) * 64 + l) * 8;
        ah[mt] = *reinterpret_cast<const bf16x8*>(wsAhi + fo);
        al[mt] = *reinterpret_cast<const bf16x8*>(wsAlo + fo);
      }
      __syncthreads();
      float4 x0 = *reinterpret_cast<const float4*>(srcX + ks * 32);
      float4 x1 = *reinterpret_cast<const float4*>(srcX + ks * 32 + 4);
      bf16x8 xhi, xlo;
      split8(x0, x1, xhi, xlo);
      *reinterpret_cast<bf16x8*>(lXhi + tid * 8) = xhi;
      *reinterpret_cast<bf16x8*>(lXlo + tid * 8) = xlo;
      __syncthreads();

      bf16x8 bh[4], bl[4];
#pragma unroll
      for (int nt = 0; nt < 4; ++nt) {
        bh[nt] = *reinterpret_cast<const bf16x8*>(lXhi + (nt * 64 + l) * 8);
        bl[nt] = *reinterpret_cast<const bf16x8*>(lXlo + (nt * 64 + l) * 8);
      }
#pragma unroll
      for (int mt = 0; mt < 4; ++mt) {
#pragma unroll
        for (int nt = 0; nt < 4; ++nt) {
          acc[mt][nt] = __builtin_amdgcn_mfma_f32_16x16x32_bf16(ah[mt], bh[nt], acc[mt][nt], 0, 0, 0);
          acc[mt][nt] = __builtin_amdgcn_mfma_f32_16x16x32_bf16(ah[mt], bl[nt], acc[mt][nt], 0, 0, 0);
          acc[mt][nt] = __builtin_amdgcn_mfma_f32_16x16x32_bf16(al[mt], bh[nt], acc[mt][nt], 0, 0, 0);
        }
      }
    }
  }

  if constexpr (MODE == 3) {
    // consume acc only: per-block scalar into u region (overwritten by MODE 0 later)
    float s = 0.0f;
#pragma unroll
    for (int mt = 0; mt < 4; ++mt)
#pragma unroll
      for (int nt = 0; nt < 4; ++nt)
#pragma unroll
        for (int r = 0; r < 4; ++r) s += acc[mt][nt][r];
#pragma unroll
    for (int off = 32; off > 0; off >>= 1) s += __shfl_xor(s, off, 64);
    if (l == 0) u_part[wm][0] = s;
    __syncthreads();
    if (tid == 0)
      u_out[(size_t)b * NS + s0] = u_part[0][0] + u_part[1][0] + u_part[2][0] + u_part[3][0];
  } else {
    // Epilogue. C/D layout: col = lane&15, row = 4*(lane>>4) + reg
    const int col = l & 15;
    const int rq  = l >> 4;
    float psum[4] = {0.f, 0.f, 0.f, 0.f};
#pragma unroll
    for (int mt = 0; mt < 4; ++mt) {
#pragma unroll
      for (int r = 0; r < 4; ++r) {
        const int h = 64 * wm + 16 * mt + 4 * rq + r;
        const float brv = br[h];
        const float qv  = ws_q[b * NH + h];
        const float vv  = v[h];
#pragma unroll
        for (int nt = 0; nt < 4; ++nt) {
          float e = acc[mt][nt][r] + brv;
          if constexpr (MODE != 1)
            e_out[(size_t)b * NH * NS + (size_t)h * NS + (s0 + 16 * nt + col)] = e;
          psum[nt] += vv * fast_tanh(qv + e);
        }
      }
    }
#pragma unroll
    for (int nt = 0; nt < 4; ++nt) {
      float p = psum[nt];
      p += __shfl_xor(p, 16, 64);
      p += __shfl_xor(p, 32, 64);
      if (l < 16) u_part[wm][16 * nt + col] = p;
    }
    __syncthreads();
    if (tid < 64) {
      float u = u_part[0][tid] + u_part[1][tid] + u_part[2][tid] + u_part[3][tid];
      u_out[(size_t)b * NS + s0 + tid] = 10.0f * fast_tanh(u);
    }
  }
}

extern "C" void kernel_launch(void* const* d_in, const int* in_sizes, int n_in,
                              void* d_out, int out_size, void* d_ws, size_t ws_size,
                              hipStream_t stream) {
  const float* query = (const float*)d_in[0];
  const float* ref   = (const float*)d_in[1];
  const float* Wq    = (const float*)d_in[2];
  const float* bq    = (const float*)d_in[3];
  const float* Wr    = (const float*)d_in[4];
  const float* br    = (const float*)d_in[5];
  const float* v     = (const float*)d_in[6];

  float* e_out = (float*)d_out;                       // [B][H][S]
  float* u_out = e_out + (size_t)NB * NH * NS;        // [B][S]

  float*  ws_q  = (float*)d_ws;
  __bf16* wsAhi = (__bf16*)((char*)d_ws + 32 * 1024);
  __bf16* wsAlo = (__bf16*)((char*)d_ws + 32 * 1024 + 128 * 1024);

  const dim3 grid(NS / 64, NB);
  prep_kernel<<<dim3(NB + 32), 256, 0, stream>>>(query, Wq, bq, Wr, ws_q, wsAhi, wsAlo);
  // probes (write only into d_out regions fully rewritten by the final real kernel)
  attn_t<2><<<grid, 256, 0, stream>>>(ref, br, v, ws_q, wsAhi, wsAlo, e_out, u_out);
  attn_t<3><<<grid, 256, 0, stream>>>(ref, br, v, ws_q, wsAhi, wsAlo, e_out, u_out);
  attn_t<1><<<grid, 256, 0, stream>>>(ref, br, v, ws_q, wsAhi, wsAlo, e_out, u_out);
  // real kernel LAST: overwrites every e and u element with correct values
  attn_t<0><<<grid, 256, 0, stream>>>(ref, br, v, ws_q, wsAhi, wsAlo, e_out, u_out);
}

// Round 9
// 186.404 us; speedup vs baseline: 2.4287x; 2.4287x over previous
//
#include <hip/hip_runtime.h>

#define NB 32      // B
#define NS 8192    // S
#define NH 256     // H
#define NR 256     // RIN
#define NQ 256     // QIN

typedef __bf16 bf16x8 __attribute__((ext_vector_type(8)));
typedef float  f32x4  __attribute__((ext_vector_type(4)));

__device__ __forceinline__ float fast_tanh(float x) {
  x = fminf(15.0f, fmaxf(-15.0f, x));
  float e = __expf(2.0f * x);
  return (e - 1.0f) * __builtin_amdgcn_rcpf(e + 1.0f);
}

// split 8 consecutive f32 into bf16 hi + bf16 lo (RNE): x ~= hi + lo
__device__ __forceinline__ void split8(float4 a, float4 b, bf16x8& hi, bf16x8& lo) {
  float x[8] = {a.x, a.y, a.z, a.w, b.x, b.y, b.z, b.w};
#pragma unroll
  for (int j = 0; j < 8; ++j) {
    __bf16 h = (__bf16)x[j];
    hi[j] = h;
    lo[j] = (__bf16)(x[j] - (float)h);
  }
}

// blocks 0..31: q[b,h] = query[b,:]@Wq[h,:] + bq[h]
// blocks 32..63: split Wr into fragment-linear hi/lo bf16: [ks][mtile][lane][8]
//   element = Wr[16*mt + (l&15)][32*ks + 8*(l>>4) + j]
__global__ __launch_bounds__(256) void prep_kernel(
    const float* __restrict__ query, const float* __restrict__ Wq,
    const float* __restrict__ bq, const float* __restrict__ Wr,
    float* __restrict__ ws_q, __bf16* __restrict__ wsAhi, __bf16* __restrict__ wsAlo) {
  const int tid = threadIdx.x;
  const int blk = blockIdx.x;
  if (blk < NB) {
    const float4* qr = reinterpret_cast<const float4*>(query + blk * NQ);
    const float4* wr = reinterpret_cast<const float4*>(Wq + tid * NQ);
    float acc = 0.0f;
#pragma unroll 8
    for (int i = 0; i < NQ / 4; ++i) {
      float4 a = qr[i], w = wr[i];
      acc += a.x * w.x + a.y * w.y + a.z * w.z + a.w * w.w;
    }
    ws_q[blk * NH + tid] = acc + bq[tid];
  } else {
    const int gid = (blk - NB) * 256 + tid;   // [ks(8)][mt(16)][lane(64)]
    const int l  = gid & 63;
    const int mt = (gid >> 6) & 15;
    const int ks = gid >> 10;
    const int row = 16 * mt + (l & 15);
    const int kb  = 32 * ks + 8 * (l >> 4);
    const float4* src = reinterpret_cast<const float4*>(Wr + row * NR + kb);
    bf16x8 hi, lo;
    split8(src[0], src[1], hi, lo);
    *reinterpret_cast<bf16x8*>(wsAhi + (size_t)gid * 8) = hi;
    *reinterpret_cast<bf16x8*>(wsAlo + (size_t)gid * 8) = lo;
  }
}

// R8: 2-phase staging (3 barriers/block total), barrier-free compute steps,
// swapped MFMA operands -> D = [s][h] so e-stores are dwordx4-vectorized.
// Block: batch b, 64 s-cols, 256 h. Wave wm owns h in [64wm, 64wm+64).
// acc[mt][nt]: mt = s-subtile (16 s), nt = h-subtile (16 h of wave's block).
__global__ __launch_bounds__(256, 3) void attn_kernel(
    const float* __restrict__ ref, const float* __restrict__ br,
    const float* __restrict__ v, const float* __restrict__ ws_q,
    const __bf16* __restrict__ wsAhi, const __bf16* __restrict__ wsAlo,
    float* __restrict__ e_out, float* __restrict__ u_out) {
  __shared__ __bf16 lXhi[4 * 2048];   // 4 k-tiles x [mt(4)][lane(64)][8] bf16
  __shared__ __bf16 lXlo[4 * 2048];
  __shared__ __align__(16) float u_part[4][64];

  const int tid = threadIdx.x;
  const int l   = tid & 63;
  const int wm  = tid >> 6;
  const int s0  = blockIdx.x * 64;
  const int b   = blockIdx.y;

  // staging source: thread stages frag slot (mt=wm, lane=l) of each k-tile:
  // 8 consecutive r of s-row (s0 + 16*wm + (l&15))
  const float* srcX = ref + (size_t)(s0 + 16 * wm + (l & 15)) * (NB * NR)
                          + (size_t)b * NR + 8 * (l >> 4);

  f32x4 acc[4][4];
  const f32x4 zero = {0.f, 0.f, 0.f, 0.f};
#pragma unroll
  for (int mt = 0; mt < 4; ++mt)
#pragma unroll
    for (int nt = 0; nt < 4; ++nt) acc[mt][nt] = zero;

  // ---- phase 0 staging: k-tiles 0..3 (k in [0,128)) ----
  float4 xs[8];
#pragma unroll
  for (int t = 0; t < 4; ++t) {
    xs[2 * t]     = *reinterpret_cast<const float4*>(srcX + t * 32);
    xs[2 * t + 1] = *reinterpret_cast<const float4*>(srcX + t * 32 + 4);
  }
#pragma unroll
  for (int t = 0; t < 4; ++t) {
    bf16x8 hi, lo;
    split8(xs[2 * t], xs[2 * t + 1], hi, lo);
    *reinterpret_cast<bf16x8*>(lXhi + t * 2048 + tid * 8) = hi;
    *reinterpret_cast<bf16x8*>(lXlo + t * 2048 + tid * 8) = lo;
  }
  __syncthreads();

  // issue phase-1 loads now; they complete under phase-0 compute
#pragma unroll
  for (int t = 0; t < 4; ++t) {
    xs[2 * t]     = *reinterpret_cast<const float4*>(srcX + 128 + t * 32);
    xs[2 * t + 1] = *reinterpret_cast<const float4*>(srcX + 128 + t * 32 + 4);
  }

  // one compute step: k-tile t (LDS), global k-step ks (for ws offsets)
  auto step = [&](int t, int ks) {
    bf16x8 wh[4], wl[4], xh[4], xl[4];
#pragma unroll
    for (int nt = 0; nt < 4; ++nt) {
      const size_t fo = ((size_t)(ks * 16 + wm * 4 + nt) * 64 + l) * 8;
      wh[nt] = *reinterpret_cast<const bf16x8*>(wsAhi + fo);
      wl[nt] = *reinterpret_cast<const bf16x8*>(wsAlo + fo);
    }
#pragma unroll
    for (int mt = 0; mt < 4; ++mt) {
      xh[mt] = *reinterpret_cast<const bf16x8*>(lXhi + t * 2048 + (mt * 64 + l) * 8);
      xl[mt] = *reinterpret_cast<const bf16x8*>(lXlo + t * 2048 + (mt * 64 + l) * 8);
    }
#pragma unroll
    for (int mt = 0; mt < 4; ++mt) {
#pragma unroll
      for (int nt = 0; nt < 4; ++nt) {
        acc[mt][nt] = __builtin_amdgcn_mfma_f32_16x16x32_bf16(xh[mt], wh[nt], acc[mt][nt], 0, 0, 0);
        acc[mt][nt] = __builtin_amdgcn_mfma_f32_16x16x32_bf16(xh[mt], wl[nt], acc[mt][nt], 0, 0, 0);
        acc[mt][nt] = __builtin_amdgcn_mfma_f32_16x16x32_bf16(xl[mt], wh[nt], acc[mt][nt], 0, 0, 0);
      }
    }
  };

  step(0, 0); step(1, 1); step(2, 2); step(3, 3);
  __syncthreads();                     // phase-0 LDS reads done; xs loads landed

  // ---- phase 1 staging: k-tiles 4..7 ----
#pragma unroll
  for (int t = 0; t < 4; ++t) {
    bf16x8 hi, lo;
    split8(xs[2 * t], xs[2 * t + 1], hi, lo);
    *reinterpret_cast<bf16x8*>(lXhi + t * 2048 + tid * 8) = hi;
    *reinterpret_cast<bf16x8*>(lXlo + t * 2048 + tid * 8) = lo;
  }
  __syncthreads();

  step(0, 4); step(1, 5); step(2, 6); step(3, 7);

  // ---- epilogue: D layout (swapped) col = lane&15 -> h, row = 4*(lane>>4)+reg -> s
  const int col = l & 15;
  const int rq  = l >> 4;
  f32x4 usum[4];
#pragma unroll
  for (int mt = 0; mt < 4; ++mt) usum[mt] = zero;

#pragma unroll
  for (int nt = 0; nt < 4; ++nt) {
    const int h = 64 * wm + 16 * nt + col;
    const float brv = br[h];
    const float qv  = ws_q[b * NH + h];
    const float vv  = v[h];
#pragma unroll
    for (int mt = 0; mt < 4; ++mt) {
      f32x4 e4 = acc[mt][nt];
#pragma unroll
      for (int r = 0; r < 4; ++r) e4[r] += brv;
      *reinterpret_cast<f32x4*>(e_out + (size_t)b * NH * NS + (size_t)h * NS
                                + (s0 + 16 * mt + 4 * rq)) = e4;
#pragma unroll
      for (int r = 0; r < 4; ++r) usum[mt][r] += vv * fast_tanh(qv + e4[r]);
    }
  }
  // reduce over the 16 h-cols in-wave
#pragma unroll
  for (int off = 1; off < 16; off <<= 1) {
#pragma unroll
    for (int mt = 0; mt < 4; ++mt)
#pragma unroll
      for (int r = 0; r < 4; ++r)
        usum[mt][r] += __shfl_xor(usum[mt][r], off, 64);
  }
  if (col == 0) {
#pragma unroll
    for (int mt = 0; mt < 4; ++mt)
      *reinterpret_cast<f32x4*>(&u_part[wm][16 * mt + 4 * rq]) = usum[mt];
  }
  __syncthreads();
  if (tid < 16) {
    f32x4 u = *reinterpret_cast<const f32x4*>(&u_part[0][4 * tid]);
#pragma unroll
    for (int w = 1; w < 4; ++w) {
      f32x4 t2 = *reinterpret_cast<const f32x4*>(&u_part[w][4 * tid]);
#pragma unroll
      for (int r = 0; r < 4; ++r) u[r] += t2[r];
    }
    f32x4 o;
#pragma unroll
    for (int r = 0; r < 4; ++r) o[r] = 10.0f * fast_tanh(u[r]);
    *reinterpret_cast<f32x4*>(u_out + (size_t)b * NS + s0 + 4 * tid) = o;
  }
}

extern "C" void kernel_launch(void* const* d_in, const int* in_sizes, int n_in,
                              void* d_out, int out_size, void* d_ws, size_t ws_size,
                              hipStream_t stream) {
  const float* query = (const float*)d_in[0];
  const float* ref   = (const float*)d_in[1];
  const float* Wq    = (const float*)d_in[2];
  const float* bq    = (const float*)d_in[3];
  const float* Wr    = (const float*)d_in[4];
  const float* br    = (const float*)d_in[5];
  const float* v     = (const float*)d_in[6];

  float* e_out = (float*)d_out;                       // [B][H][S]
  float* u_out = e_out + (size_t)NB * NH * NS;        // [B][S]

  float*  ws_q  = (float*)d_ws;
  __bf16* wsAhi = (__bf16*)((char*)d_ws + 32 * 1024);
  __bf16* wsAlo = (__bf16*)((char*)d_ws + 32 * 1024 + 128 * 1024);

  prep_kernel<<<dim3(NB + 32), 256, 0, stream>>>(query, Wq, bq, Wr, ws_q, wsAhi, wsAlo);
  attn_kernel<<<dim3(NS / 64, NB), 256, 0, stream>>>(ref, br, v, ws_q, wsAhi, wsAlo, e_out, u_out);
}